// Round 15
// baseline (522.997 us; speedup 1.0000x reference)
//
#include <hip/hip_runtime.h>

#define N_NODES 100000
#define N_EDGES 1600000
#define N_GRAPHS 256
#define NCHUNKS ((N_NODES + 255) / 256)   // 391
#define RANGE_PER_XCD 12500               // 100000 / 8

__device__ __forceinline__ float lrelu(float v) { return v > 0.f ? v : 0.01f * v; }

// bf16 storage helpers (RNE)
__device__ __forceinline__ unsigned short f2bf(float f) {
    unsigned int u = __float_as_uint(f);
    return (unsigned short)((u + 0x7FFFu + ((u >> 16) & 1u)) >> 16);
}
__device__ __forceinline__ float bf2f(unsigned short h) {
    return __uint_as_float(((unsigned int)h) << 16);
}
__device__ __forceinline__ float blo(unsigned int v) { return __uint_as_float(v << 16); }
__device__ __forceinline__ float bhi(unsigned int v) { return __uint_as_float(v & 0xFFFF0000u); }
__device__ __forceinline__ int ntl(const int* p) { return __builtin_nontemporal_load(p); }

// ============ CSR build ============
__global__ void degree_kernel(const int* __restrict__ dst, int* __restrict__ deg) {
    int e = blockIdx.x * 256 + threadIdx.x;
    if (e < N_EDGES) atomicAdd(&deg[ntl(&dst[e])], 1);
}

__global__ void scan_chunks_kernel(const int* __restrict__ deg, int* __restrict__ base,
                                   int* __restrict__ chunkSum) {
    __shared__ int s[256];
    int t = threadIdx.x;
    int i = blockIdx.x * 256 + t;
    int v = (i < N_NODES) ? deg[i] : 0;
    s[t] = v;
    __syncthreads();
    for (int off = 1; off < 256; off <<= 1) {
        int add = (t >= off) ? s[t - off] : 0;
        __syncthreads();
        s[t] += add;
        __syncthreads();
    }
    if (i < N_NODES) base[i + 1] = s[t];
    if (t == 255) chunkSum[blockIdx.x] = s[255];
    if (i == 0) base[0] = 0;
}

__global__ void scan_tops_kernel(int* __restrict__ chunkSum) {
    __shared__ int s[512];
    int t = threadIdx.x;
    s[t] = (t < NCHUNKS) ? chunkSum[t] : 0;
    __syncthreads();
    for (int off = 1; off < 512; off <<= 1) {
        int add = (t >= off) ? s[t - off] : 0;
        __syncthreads();
        s[t] += add;
        __syncthreads();
    }
    if (t < NCHUNKS) chunkSum[t] = s[t];
}

__global__ void add_offsets_kernel(int* __restrict__ base, const int* __restrict__ chunkSum) {
    int i = blockIdx.x * 256 + threadIdx.x;
    if (i < N_NODES) {
        int b = i / 256;
        if (b > 0) base[i + 1] += chunkSum[b - 1];
    }
}

// XCD-range-partitioned scatter; NT loads keep streamed src/dst out of L2 so
// partially-filled adj lines stay resident and coalesce their writebacks.
__global__ void fill_adj_xcd(const int* __restrict__ src, const int* __restrict__ dst,
                             const int* __restrict__ base, int* __restrict__ cursor,
                             int* __restrict__ adj) {
    int lo = (blockIdx.x & 7) * RANGE_PER_XCD;
    int hi = lo + RANGE_PER_XCD;
    int e0 = (blockIdx.x >> 3) * 1024 + threadIdx.x;
#pragma unroll
    for (int i = 0; i < 4; ++i) {
        int e = e0 + i * 256;
        if (e < N_EDGES) {
            int d = ntl(&dst[e]);
            if (d >= lo && d < hi) {
                int pos = atomicAdd(&cursor[d], 1);
                adj[base[d] + pos] = ntl(&src[e]);
            }
        }
    }
}

// ============ matmul: X[N,DIN] @ W[DIN,DOUT] -> T bf16 rows, optional bias+lrelu ============
template <int DIN, int DOUT, bool IN_F32, bool BIAS, bool RELU>
__global__ void matmul_bf16(const void* __restrict__ Xv, const float* __restrict__ W,
                            unsigned short* __restrict__ T, const float* __restrict__ bias) {
    constexpr int PAIRS = DOUT / 2;
    __shared__ float xs[64 * DIN];
    __shared__ float wsm[DIN * DOUT];
    const int n0 = blockIdx.x * 64;
    const bool full = (n0 + 64 <= N_NODES);
    for (int i = threadIdx.x; i < DIN * DOUT; i += 256) wsm[i] = W[i];
    if (IN_F32) {
        const float4* X4 = (const float4*)Xv;
        constexpr int V = DIN / 4;   // float4 per row
        for (int i = threadIdx.x; i < 64 * V; i += 256) {
            int r = i / V, c = i - r * V;
            int node = n0 + r;
            float4 v = make_float4(0.f, 0.f, 0.f, 0.f);
            if (full || node < N_NODES) v = X4[(size_t)node * V + c];
            ((float4*)xs)[i] = v;
        }
    } else {
        const unsigned int* X2 = (const unsigned int*)Xv;   // 2 bf16 per uint
        constexpr int V = DIN / 2;
        for (int i = threadIdx.x; i < 64 * V; i += 256) {
            int r = i / V, c = i - r * V;
            int node = n0 + r;
            unsigned int v = (full || node < N_NODES) ? X2[(size_t)node * V + c] : 0u;
            xs[r * DIN + 2 * c]     = blo(v);
            xs[r * DIN + 2 * c + 1] = bhi(v);
        }
    }
    __syncthreads();
    unsigned int* Tu = (unsigned int*)T;
    for (int o = threadIdx.x; o < 64 * PAIRS; o += 256) {
        int r = o / PAIRS, jp = o - r * PAIRS;
        int node = n0 + r;
        if (node < N_NODES) {
            float a0 = 0.f, a1 = 0.f;
            const float* xr = xs + r * DIN;
#pragma unroll
            for (int k = 0; k < DIN; ++k) {
                float xv = xr[k];
                a0 = fmaf(xv, wsm[k * DOUT + 2 * jp], a0);
                a1 = fmaf(xv, wsm[k * DOUT + 2 * jp + 1], a1);
            }
            if (BIAS) { a0 += bias[2 * jp]; a1 += bias[2 * jp + 1]; }
            if (RELU) { a0 = lrelu(a0); a1 = lrelu(a1); }
            Tu[(size_t)node * PAIRS + jp] = ((unsigned int)f2bf(a1) << 16) | f2bf(a0);
        }
    }
}

// ============ gather edge-loop (4x ILP), shared by all gather kernels ============
template <int PAIRS>
__device__ __forceinline__ void gather_loop(const unsigned int* __restrict__ Tu,
                                            const int* __restrict__ adj,
                                            int e0, int e1, int j, float& ra0, float& ra1) {
    float a0 = 0.f, a1 = 0.f, c0 = 0.f, c1 = 0.f;
    int k = e0;
    for (; k + 3 < e1; k += 4) {
        int s0 = ntl(&adj[k]), s1 = ntl(&adj[k + 1]), s2 = ntl(&adj[k + 2]), s3 = ntl(&adj[k + 3]);
        unsigned int v0 = Tu[(size_t)s0 * PAIRS + j];
        unsigned int v1 = Tu[(size_t)s1 * PAIRS + j];
        unsigned int v2 = Tu[(size_t)s2 * PAIRS + j];
        unsigned int v3 = Tu[(size_t)s3 * PAIRS + j];
        a0 += blo(v0); a1 += bhi(v0);
        c0 += blo(v1); c1 += bhi(v1);
        a0 += blo(v2); a1 += bhi(v2);
        c0 += blo(v3); c1 += bhi(v3);
    }
    for (; k < e1; ++k) {
        int s = ntl(&adj[k]);
        unsigned int v = Tu[(size_t)s * PAIRS + j];
        a0 += blo(v); a1 += bhi(v);
    }
    ra0 = a0 + c0;
    ra1 = a1 + c1;
}

// ============ standalone CSR gather-aggregate (bf16 pairs) ============
template <int DOUT, bool BIAS, bool RELU>
__global__ void gather_agg_bf16(const unsigned short* __restrict__ T, const int* __restrict__ base,
                                const int* __restrict__ adj, const float* __restrict__ b,
                                unsigned short* __restrict__ out) {
    constexpr int PAIRS = DOUT / 2;
    int gi = blockIdx.x * 256 + threadIdx.x;
    int node = gi / PAIRS;
    int j = gi - node * PAIRS;
    if (node >= N_NODES) return;
    const unsigned int* Tu = (const unsigned int*)T;
    float a0, a1;
    gather_loop<PAIRS>(Tu, adj, base[node], base[node + 1], j, a0, a1);
    if (BIAS) { a0 += b[2 * j]; a1 += b[2 * j + 1]; }
    if (RELU) { a0 = lrelu(a0); a1 = lrelu(a1); }
    unsigned int pv = ((unsigned int)f2bf(a1) << 16) | f2bf(a0);
    __builtin_nontemporal_store(pv, &((unsigned int*)out)[(size_t)node * PAIRS + j]);
}

// ============ fused: s2 = agg(h1)[16]; h2 = lrelu(s2@W2+b2)[16->32] ============
__global__ void gather16_mm32(const unsigned short* __restrict__ T, const int* __restrict__ base,
                              const int* __restrict__ adj, const float* __restrict__ W,
                              const float* __restrict__ b, unsigned short* __restrict__ out) {
    __shared__ float s2[32][18];
    __shared__ float wsm[16 * 32];
    for (int i = threadIdx.x; i < 16 * 32; i += 256) wsm[i] = W[i];
    int tid = threadIdx.x;
    int n = tid >> 3, j = tid & 7;
    int node = blockIdx.x * 32 + n;
    const unsigned int* Tu = (const unsigned int*)T;
    float a0 = 0.f, a1 = 0.f;
    if (node < N_NODES) gather_loop<8>(Tu, adj, base[node], base[node + 1], j, a0, a1);
    s2[n][2 * j] = a0;
    s2[n][2 * j + 1] = a1;
    __syncthreads();
    unsigned int* ou = (unsigned int*)out;
    for (int idx = tid; idx < 512; idx += 256) {
        int nn = idx >> 4, jp = idx & 15;
        int onode = blockIdx.x * 32 + nn;
        if (onode < N_NODES) {
            float x0 = b[2 * jp], x1 = b[2 * jp + 1];
#pragma unroll
            for (int k = 0; k < 16; ++k) {
                float xv = s2[nn][k];
                x0 = fmaf(xv, wsm[k * 32 + 2 * jp], x0);
                x1 = fmaf(xv, wsm[k * 32 + 2 * jp + 1], x1);
            }
            x0 = lrelu(x0); x1 = lrelu(x1);
            unsigned int pv = ((unsigned int)f2bf(x1) << 16) | f2bf(x0);
            __builtin_nontemporal_store(pv, &ou[(size_t)onode * 16 + jp]);
        }
    }
}

// ============ fused: s3 = agg(h2)[32]; h3 = lrelu(s3@W3+b3)[32->64] ============
__global__ void gather32_mm64(const unsigned short* __restrict__ T, const int* __restrict__ base,
                              const int* __restrict__ adj, const float* __restrict__ W,
                              const float* __restrict__ b, unsigned short* __restrict__ out) {
    __shared__ float s3[16][34];
    __shared__ float wsm[32 * 64];
    for (int i = threadIdx.x; i < 32 * 64; i += 256) wsm[i] = W[i];
    int tid = threadIdx.x;
    int n = tid >> 4, j = tid & 15;
    int node = blockIdx.x * 16 + n;
    const unsigned int* Tu = (const unsigned int*)T;
    float a0 = 0.f, a1 = 0.f;
    if (node < N_NODES) gather_loop<16>(Tu, adj, base[node], base[node + 1], j, a0, a1);
    s3[n][2 * j] = a0;
    s3[n][2 * j + 1] = a1;
    __syncthreads();
    unsigned int* ou = (unsigned int*)out;
    for (int idx = tid; idx < 512; idx += 256) {
        int nn = idx >> 5, jp = idx & 31;
        int onode = blockIdx.x * 16 + nn;
        if (onode < N_NODES) {
            float x0 = b[2 * jp], x1 = b[2 * jp + 1];
#pragma unroll
            for (int k = 0; k < 32; ++k) {
                float xv = s3[nn][k];
                x0 = fmaf(xv, wsm[k * 64 + 2 * jp], x0);
                x1 = fmaf(xv, wsm[k * 64 + 2 * jp + 1], x1);
            }
            x0 = lrelu(x0); x1 = lrelu(x1);
            unsigned int pv = ((unsigned int)f2bf(x1) << 16) | f2bf(x0);
            __builtin_nontemporal_store(pv, &ou[(size_t)onode * 32 + jp]);
        }
    }
}

// ============ BatchNorm stats (bf16 row input) ============
__global__ void bn_partial_kernel(const unsigned short* __restrict__ H, float* __restrict__ sum,
                                  float* __restrict__ ssum) {
    int tid = threadIdx.x;
    int j = tid % 50;
    int sub = tid / 50;
    float s = 0.f, ss = 0.f;
    if (tid < 250) {
        for (int node = blockIdx.x * 5 + sub; node < N_NODES; node += gridDim.x * 5) {
            float v = bf2f(H[(size_t)node * 50 + j]);
            s += v;
            ss += v * v;
        }
    }
    __shared__ float ls[256], lss[256];
    ls[tid] = s;
    lss[tid] = ss;
    __syncthreads();
    if (tid < 50) {
        float a = ls[tid] + ls[tid + 50] + ls[tid + 100] + ls[tid + 150] + ls[tid + 200];
        float c = lss[tid] + lss[tid + 50] + lss[tid + 100] + lss[tid + 150] + lss[tid + 200];
        atomicAdd(&sum[tid], a);
        atomicAdd(&ssum[tid], c);
    }
}

__global__ void bn_finalize_kernel(const float* __restrict__ sum, const float* __restrict__ ssum,
                                   float* __restrict__ mu, float* __restrict__ rsig) {
    int j = threadIdx.x;
    if (j < 50) {
        float m = sum[j] / (float)N_NODES;
        float var = ssum[j] / (float)N_NODES - m * m;
        mu[j] = m;
        rsig[j] = rsqrtf(fmaxf(var, 0.f) + 1e-5f);
    }
}

// ============ graph boundary search (batch is sorted) ============
__global__ void find_bounds_kernel(const int* __restrict__ batch, int* __restrict__ bounds) {
    int g = blockIdx.x * blockDim.x + threadIdx.x;
    if (g > N_GRAPHS) return;
    int lo = 0, hi = N_NODES;
    while (lo < hi) {
        int mid = (lo + hi) >> 1;
        if (batch[mid] < g) lo = mid + 1; else hi = mid;
    }
    bounds[g] = lo;
}

// ============ BN apply + lrelu + segmented pool: one block per graph ============
__global__ void pool_seg_kernel(const unsigned short* __restrict__ H, const int* __restrict__ bounds,
                                const float* __restrict__ mu, const float* __restrict__ rsig,
                                const float* __restrict__ gamma, const float* __restrict__ beta,
                                float* __restrict__ G) {
    int g = blockIdx.x;
    int s = bounds[g], e = bounds[g + 1];
    int tid = threadIdx.x;
    int j = tid % 50;
    int sub = tid / 50;     // 0..4 for tid<250
    float acc = 0.f;
    if (tid < 250) {
        float scale = rsig[j] * gamma[j];
        float shift = beta[j] - mu[j] * scale;
        for (int n = s + sub; n < e; n += 5) {
            float v = fmaf(bf2f(H[(size_t)n * 50 + j]), scale, shift);
            acc += lrelu(v);
        }
    }
    __shared__ float ls[256];
    ls[tid] = acc;
    __syncthreads();
    if (tid < 50) {
        G[g * 50 + tid] = ls[tid] + ls[tid + 50] + ls[tid + 100] + ls[tid + 150] + ls[tid + 200];
    }
}

// ============ MLP head ============
__global__ void mlp_kernel(const float* __restrict__ G,
                           const float* __restrict__ fc1W, const float* __restrict__ fc1b,
                           const float* __restrict__ fc2W, const float* __restrict__ fc2b,
                           const float* __restrict__ fc3W, const float* __restrict__ fc3b,
                           float* __restrict__ out) {
    int g = blockIdx.x * blockDim.x + threadIdx.x;
    if (g >= N_GRAPHS) return;
    float a[50];
#pragma unroll
    for (int k = 0; k < 50; ++k) a[k] = G[g * 50 + k];
    float h1[30];
#pragma unroll
    for (int j = 0; j < 30; ++j) {
        float acc = fc1b[j];
#pragma unroll
        for (int k = 0; k < 50; ++k) acc = fmaf(a[k], fc1W[k * 30 + j], acc);
        h1[j] = lrelu(acc);
    }
    float h2[20];
#pragma unroll
    for (int j = 0; j < 20; ++j) {
        float acc = fc2b[j];
#pragma unroll
        for (int k = 0; k < 30; ++k) acc = fmaf(h1[k], fc2W[k * 20 + j], acc);
        h2[j] = lrelu(acc);
    }
    float z0 = fc3b[0], z1 = fc3b[1];
#pragma unroll
    for (int k = 0; k < 20; ++k) {
        z0 = fmaf(h2[k], fc3W[k * 2 + 0], z0);
        z1 = fmaf(h2[k], fc3W[k * 2 + 1], z1);
    }
    float m = fmaxf(z0, z1);
    float lse = m + logf(expf(z0 - m) + expf(z1 - m));
    out[g * 2 + 0] = z0 - lse;
    out[g * 2 + 1] = z1 - lse;
}

extern "C" void kernel_launch(void* const* d_in, const int* in_sizes, int n_in,
                              void* d_out, int out_size, void* d_ws, size_t ws_size,
                              hipStream_t stream) {
    const float* x     = (const float*)d_in[0];
    const int*   ei    = (const int*)d_in[1];
    const int*   batch = (const int*)d_in[2];
    const float* W1 = (const float*)d_in[3];  const float* b1 = (const float*)d_in[4];
    const float* W2 = (const float*)d_in[5];  const float* b2 = (const float*)d_in[6];
    const float* W3 = (const float*)d_in[7];  const float* b3 = (const float*)d_in[8];
    const float* W4 = (const float*)d_in[9];  const float* b4 = (const float*)d_in[10];
    const float* bng = (const float*)d_in[11]; const float* bnb = (const float*)d_in[12];
    const float* fc1W = (const float*)d_in[13]; const float* fc1b = (const float*)d_in[14];
    const float* fc2W = (const float*)d_in[15]; const float* fc2b = (const float*)d_in[16];
    const float* fc3W = (const float*)d_in[17]; const float* fc3b = (const float*)d_in[18];

    const int* src = ei;
    const int* dst = ei + N_EDGES;

    // ---- workspace layout ----
    char* w = (char*)d_ws;
    unsigned short* bufA = (unsigned short*)w;      w += (size_t)6400000 * 2;  // 12.8 MB
    unsigned short* bufB = (unsigned short*)w;      w += (size_t)6400000 * 2;  // 12.8 MB
    int*   adj  = (int*)w;                          w += (size_t)N_EDGES * 4;  // 6.4 MB
    int*   deg  = (int*)w;                          w += (size_t)N_NODES * 4;
    int*   cursor = (int*)w;                        w += (size_t)N_NODES * 4;
    int*   base = (int*)w;                          w += (size_t)(N_NODES + 1) * 4;
    int*   chunkSum = (int*)w;                      w += 512 * 4;
    float* bnsum = (float*)w;                       w += 64 * 4;
    float* bnssum = (float*)w;                      w += 64 * 4;
    float* mu   = (float*)w;                        w += 64 * 4;
    float* rsig = (float*)w;                        w += 64 * 4;
    int*   bounds = (int*)w;                        w += (N_GRAPHS + 1) * 4;
    float* G    = (float*)w;                        w += (size_t)N_GRAPHS * 50 * 4;

    dim3 blk(256);
    const int edgeBlocks = (N_EDGES + 255) / 256;
    const int mmBlocks = (N_NODES + 63) / 64;

    // ---- CSR build (by dst) ----
    hipMemsetAsync(deg, 0, (size_t)N_NODES * 4, stream);
    hipMemsetAsync(cursor, 0, (size_t)N_NODES * 4, stream);
    degree_kernel<<<edgeBlocks, blk, 0, stream>>>(dst, deg);
    scan_chunks_kernel<<<NCHUNKS, blk, 0, stream>>>(deg, base, chunkSum);
    scan_tops_kernel<<<1, 512, 0, stream>>>(chunkSum);
    add_offsets_kernel<<<(N_NODES + 255) / 256, blk, 0, stream>>>(base, chunkSum);
    fill_adj_xcd<<<8 * ((N_EDGES + 1023) / 1024), blk, 0, stream>>>(src, dst, base, cursor, adj);
    find_bounds_kernel<<<2, 256, 0, stream>>>(batch, bounds);

    // ---- L1: T1 = x @ W1 [128->16]; h1 = lrelu(agg(T1) + b1) ----
    matmul_bf16<128, 16, true, false, false><<<mmBlocks, blk, 0, stream>>>(x, W1, bufA, nullptr);
    gather_agg_bf16<16, true, true><<<(N_NODES * 8 + 255) / 256, blk, 0, stream>>>(bufA, base, adj, b1, bufB);

    // ---- L2 fused: s2 = agg(h1); h2 = lrelu(s2 @ W2 + b2) [16->32] ----
    gather16_mm32<<<(N_NODES + 31) / 32, blk, 0, stream>>>(bufB, base, adj, W2, b2, bufA);

    // ---- L3 fused: s3 = agg(h2); h3 = lrelu(s3 @ W3 + b3) [32->64] ----
    gather32_mm64<<<(N_NODES + 15) / 16, blk, 0, stream>>>(bufA, base, adj, W3, b3, bufB);

    // ---- L4: T4 = h3 @ W4 [64->50]; h4 = agg(T4) + b4 ----
    matmul_bf16<64, 50, false, false, false><<<mmBlocks, blk, 0, stream>>>(bufB, W4, bufA, nullptr);
    gather_agg_bf16<50, true, false><<<(N_NODES * 25 + 255) / 256, blk, 0, stream>>>(bufA, base, adj, b4, bufB);

    // ---- BatchNorm stats ----
    hipMemsetAsync(bnsum, 0, 128 * 4, stream);
    bn_partial_kernel<<<256, blk, 0, stream>>>(bufB, bnsum, bnssum);
    bn_finalize_kernel<<<1, 64, 0, stream>>>(bnsum, bnssum, mu, rsig);

    // ---- BN apply + lrelu + segmented pool (no atomics) ----
    pool_seg_kernel<<<N_GRAPHS, blk, 0, stream>>>(bufB, bounds, mu, rsig, bng, bnb, G);

    // ---- MLP head ----
    mlp_kernel<<<1, 256, 0, stream>>>(G, fc1W, fc1b, fc2W, fc2b, fc3W, fc3b, (float*)d_out);
}

// Round 16
// 462.964 us; speedup vs baseline: 1.1297x; 1.1297x over previous
//
#include <hip/hip_runtime.h>

#define N_NODES 100000
#define N_EDGES 1600000
#define N_GRAPHS 256
#define NCHUNKS ((N_NODES + 255) / 256)   // 391
#define RANGE_PER_XCD 12500               // 100000 / 8
#define FILL_BLOCKS 12504                 // 8 * 1563 edge-chunks
#define MM1_BLOCKS 3125                   // 100000 / 32 exactly
#define FUSED_BLOCKS (FILL_BLOCKS + MM1_BLOCKS)   // 15629 = 5 * 3125 + 12504? no: 15629

__device__ __forceinline__ float lrelu(float v) { return v > 0.f ? v : 0.01f * v; }

// bf16 storage helpers (RNE)
__device__ __forceinline__ unsigned short f2bf(float f) {
    unsigned int u = __float_as_uint(f);
    return (unsigned short)((u + 0x7FFFu + ((u >> 16) & 1u)) >> 16);
}
__device__ __forceinline__ float bf2f(unsigned short h) {
    return __uint_as_float(((unsigned int)h) << 16);
}
__device__ __forceinline__ float blo(unsigned int v) { return __uint_as_float(v << 16); }
__device__ __forceinline__ float bhi(unsigned int v) { return __uint_as_float(v & 0xFFFF0000u); }

// ============ CSR build ============
__global__ void degree_kernel(const int* __restrict__ dst, int* __restrict__ deg) {
    int e = blockIdx.x * 256 + threadIdx.x;
    if (e < N_EDGES) atomicAdd(&deg[dst[e]], 1);
}

__global__ void scan_chunks_kernel(const int* __restrict__ deg, int* __restrict__ base,
                                   int* __restrict__ chunkSum) {
    __shared__ int s[256];
    int t = threadIdx.x;
    int i = blockIdx.x * 256 + t;
    int v = (i < N_NODES) ? deg[i] : 0;
    s[t] = v;
    __syncthreads();
    for (int off = 1; off < 256; off <<= 1) {
        int add = (t >= off) ? s[t - off] : 0;
        __syncthreads();
        s[t] += add;
        __syncthreads();
    }
    if (i < N_NODES) base[i + 1] = s[t];
    if (t == 255) chunkSum[blockIdx.x] = s[255];
    if (i == 0) base[0] = 0;
}

__global__ void scan_tops_kernel(int* __restrict__ chunkSum) {
    __shared__ int s[512];
    int t = threadIdx.x;
    s[t] = (t < NCHUNKS) ? chunkSum[t] : 0;
    __syncthreads();
    for (int off = 1; off < 512; off <<= 1) {
        int add = (t >= off) ? s[t - off] : 0;
        __syncthreads();
        s[t] += add;
        __syncthreads();
    }
    if (t < NCHUNKS) chunkSum[t] = s[t];
}

__global__ void add_offsets_kernel(int* __restrict__ base, const int* __restrict__ chunkSum) {
    int i = blockIdx.x * 256 + threadIdx.x;
    if (i < N_NODES) {
        int b = i / 256;
        if (b > 0) base[i + 1] += chunkSum[b - 1];
    }
}

// ============ FUSED: XCD-partitioned fill_adj  ∥  matmul L1 (x@W1, 32-node tiles) ============
// Every 5th block is a matmul block; the rest are fill blocks (12504 fill + 3125 mm).
// Roles are independent (fill writes adj; mm writes T1) and co-resident on CUs,
// overlapping the BW/latency-bound scatter with the compute-bound matmul.
__global__ void fill_and_mm1(const int* __restrict__ src, const int* __restrict__ dst,
                             const int* __restrict__ base, int* __restrict__ cursor,
                             int* __restrict__ adj,
                             const float* __restrict__ x, const float* __restrict__ W1,
                             unsigned short* __restrict__ T1) {
    __shared__ float lds[32 * 128 + 128 * 16];   // xs (16KB) + wsm (8KB)
    int bid = blockIdx.x;
    int tid = threadIdx.x;
    bool is_mm = ((bid % 5) == 4);
    if (!is_mm) {
        int fi = (bid / 5) * 4 + (bid % 5);      // 0..12503
        if (fi < FILL_BLOCKS) {
            int lo = (fi & 7) * RANGE_PER_XCD;
            int hi = lo + RANGE_PER_XCD;
            int e0 = (fi >> 3) * 1024 + tid;
#pragma unroll
            for (int i = 0; i < 4; ++i) {
                int e = e0 + i * 256;
                if (e < N_EDGES) {
                    int d = dst[e];
                    if (d >= lo && d < hi) {
                        int pos = atomicAdd(&cursor[d], 1);
                        adj[base[d] + pos] = src[e];
                    }
                }
            }
        }
    } else {
        int mb = bid / 5;                        // 0..3124
        float* xs = lds;                         // 32 x 128
        float* wsm = lds + 32 * 128;             // 128 x 16
        const int n0 = mb * 32;                  // always full (32*3125 = 100000)
        for (int i = tid; i < 128 * 16; i += 256) wsm[i] = W1[i];
        const float4* X4 = (const float4*)x;     // 32 float4 per row
        for (int i = tid; i < 32 * 32; i += 256) {
            int r = i >> 5, c = i & 31;
            ((float4*)xs)[i] = X4[(size_t)(n0 + r) * 32 + c];
        }
        __syncthreads();
        int r = tid >> 3, jp = tid & 7;          // 32 rows x 8 pairs = 256 outputs
        float a0 = 0.f, a1 = 0.f;
        const float* xr = xs + r * 128;
#pragma unroll
        for (int k = 0; k < 128; ++k) {
            float xv = xr[k];
            a0 = fmaf(xv, wsm[k * 16 + 2 * jp], a0);
            a1 = fmaf(xv, wsm[k * 16 + 2 * jp + 1], a1);
        }
        ((unsigned int*)T1)[(size_t)(n0 + r) * 8 + jp] = ((unsigned int)f2bf(a1) << 16) | f2bf(a0);
    }
}

// ============ matmul: X[N,DIN] @ W[DIN,DOUT] -> T bf16 rows, optional bias+lrelu ============
template <int DIN, int DOUT, bool IN_F32, bool BIAS, bool RELU>
__global__ void matmul_bf16(const void* __restrict__ Xv, const float* __restrict__ W,
                            unsigned short* __restrict__ T, const float* __restrict__ bias) {
    constexpr int PAIRS = DOUT / 2;
    __shared__ float xs[64 * DIN];
    __shared__ float wsm[DIN * DOUT];
    const int n0 = blockIdx.x * 64;
    const bool full = (n0 + 64 <= N_NODES);
    for (int i = threadIdx.x; i < DIN * DOUT; i += 256) wsm[i] = W[i];
    if (IN_F32) {
        const float4* X4 = (const float4*)Xv;
        constexpr int V = DIN / 4;
        for (int i = threadIdx.x; i < 64 * V; i += 256) {
            int r = i / V, c = i - r * V;
            int node = n0 + r;
            float4 v = make_float4(0.f, 0.f, 0.f, 0.f);
            if (full || node < N_NODES) v = X4[(size_t)node * V + c];
            ((float4*)xs)[i] = v;
        }
    } else {
        const unsigned int* X2 = (const unsigned int*)Xv;
        constexpr int V = DIN / 2;
        for (int i = threadIdx.x; i < 64 * V; i += 256) {
            int r = i / V, c = i - r * V;
            int node = n0 + r;
            unsigned int v = (full || node < N_NODES) ? X2[(size_t)node * V + c] : 0u;
            xs[r * DIN + 2 * c]     = blo(v);
            xs[r * DIN + 2 * c + 1] = bhi(v);
        }
    }
    __syncthreads();
    unsigned int* Tu = (unsigned int*)T;
    for (int o = threadIdx.x; o < 64 * PAIRS; o += 256) {
        int r = o / PAIRS, jp = o - r * PAIRS;
        int node = n0 + r;
        if (node < N_NODES) {
            float a0 = 0.f, a1 = 0.f;
            const float* xr = xs + r * DIN;
#pragma unroll
            for (int k = 0; k < DIN; ++k) {
                float xv = xr[k];
                a0 = fmaf(xv, wsm[k * DOUT + 2 * jp], a0);
                a1 = fmaf(xv, wsm[k * DOUT + 2 * jp + 1], a1);
            }
            if (BIAS) { a0 += bias[2 * jp]; a1 += bias[2 * jp + 1]; }
            if (RELU) { a0 = lrelu(a0); a1 = lrelu(a1); }
            Tu[(size_t)node * PAIRS + jp] = ((unsigned int)f2bf(a1) << 16) | f2bf(a0);
        }
    }
}

// ============ CSR gather-aggregate (bf16 pairs), exact-PAIRS lanes, 4x-unrolled ILP ============
template <int DOUT, bool BIAS, bool RELU>
__global__ void gather_agg_bf16(const unsigned short* __restrict__ T, const int* __restrict__ base,
                                const int* __restrict__ adj, const float* __restrict__ b,
                                unsigned short* __restrict__ out) {
    constexpr int PAIRS = DOUT / 2;                       // 8, 16, 25
    int gi = blockIdx.x * 256 + threadIdx.x;
    int node = gi / PAIRS;                                // const div -> magic mul
    int j = gi - node * PAIRS;
    if (node >= N_NODES) return;
    const unsigned int* Tu = (const unsigned int*)T;
    int e0 = base[node], e1 = base[node + 1];
    float a0 = 0.f, a1 = 0.f, c0 = 0.f, c1 = 0.f;
    int k = e0;
    for (; k + 3 < e1; k += 4) {
        int s0 = adj[k], s1 = adj[k + 1], s2 = adj[k + 2], s3 = adj[k + 3];
        unsigned int v0 = Tu[(size_t)s0 * PAIRS + j];
        unsigned int v1 = Tu[(size_t)s1 * PAIRS + j];
        unsigned int v2 = Tu[(size_t)s2 * PAIRS + j];
        unsigned int v3 = Tu[(size_t)s3 * PAIRS + j];
        a0 += blo(v0); a1 += bhi(v0);
        c0 += blo(v1); c1 += bhi(v1);
        a0 += blo(v2); a1 += bhi(v2);
        c0 += blo(v3); c1 += bhi(v3);
    }
    for (; k < e1; ++k) {
        int s = adj[k];
        unsigned int v = Tu[(size_t)s * PAIRS + j];
        a0 += blo(v); a1 += bhi(v);
    }
    a0 += c0; a1 += c1;
    if (BIAS) { a0 += b[2 * j]; a1 += b[2 * j + 1]; }
    if (RELU) { a0 = lrelu(a0); a1 = lrelu(a1); }
    ((unsigned int*)out)[(size_t)node * PAIRS + j] = ((unsigned int)f2bf(a1) << 16) | f2bf(a0);
}

// ============ BatchNorm stats (bf16 row input) ============
__global__ void bn_partial_kernel(const unsigned short* __restrict__ H, float* __restrict__ sum,
                                  float* __restrict__ ssum) {
    int tid = threadIdx.x;
    int j = tid % 50;
    int sub = tid / 50;
    float s = 0.f, ss = 0.f;
    if (tid < 250) {
        for (int node = blockIdx.x * 5 + sub; node < N_NODES; node += gridDim.x * 5) {
            float v = bf2f(H[(size_t)node * 50 + j]);
            s += v;
            ss += v * v;
        }
    }
    __shared__ float ls[256], lss[256];
    ls[tid] = s;
    lss[tid] = ss;
    __syncthreads();
    if (tid < 50) {
        float a = ls[tid] + ls[tid + 50] + ls[tid + 100] + ls[tid + 150] + ls[tid + 200];
        float c = lss[tid] + lss[tid + 50] + lss[tid + 100] + lss[tid + 150] + lss[tid + 200];
        atomicAdd(&sum[tid], a);
        atomicAdd(&ssum[tid], c);
    }
}

__global__ void bn_finalize_kernel(const float* __restrict__ sum, const float* __restrict__ ssum,
                                   float* __restrict__ mu, float* __restrict__ rsig) {
    int j = threadIdx.x;
    if (j < 50) {
        float m = sum[j] / (float)N_NODES;
        float var = ssum[j] / (float)N_NODES - m * m;
        mu[j] = m;
        rsig[j] = rsqrtf(fmaxf(var, 0.f) + 1e-5f);
    }
}

// ============ graph boundary search (batch is sorted) ============
__global__ void find_bounds_kernel(const int* __restrict__ batch, int* __restrict__ bounds) {
    int g = blockIdx.x * blockDim.x + threadIdx.x;
    if (g > N_GRAPHS) return;
    int lo = 0, hi = N_NODES;
    while (lo < hi) {
        int mid = (lo + hi) >> 1;
        if (batch[mid] < g) lo = mid + 1; else hi = mid;
    }
    bounds[g] = lo;
}

// ============ BN apply + lrelu + segmented pool: one block per graph ============
__global__ void pool_seg_kernel(const unsigned short* __restrict__ H, const int* __restrict__ bounds,
                                const float* __restrict__ mu, const float* __restrict__ rsig,
                                const float* __restrict__ gamma, const float* __restrict__ beta,
                                float* __restrict__ G) {
    int g = blockIdx.x;
    int s = bounds[g], e = bounds[g + 1];
    int tid = threadIdx.x;
    int j = tid % 50;
    int sub = tid / 50;     // 0..4 for tid<250
    float acc = 0.f;
    if (tid < 250) {
        float scale = rsig[j] * gamma[j];
        float shift = beta[j] - mu[j] * scale;
        for (int n = s + sub; n < e; n += 5) {
            float v = fmaf(bf2f(H[(size_t)n * 50 + j]), scale, shift);
            acc += lrelu(v);
        }
    }
    __shared__ float ls[256];
    ls[tid] = acc;
    __syncthreads();
    if (tid < 50) {
        G[g * 50 + tid] = ls[tid] + ls[tid + 50] + ls[tid + 100] + ls[tid + 150] + ls[tid + 200];
    }
}

// ============ MLP head ============
__global__ void mlp_kernel(const float* __restrict__ G,
                           const float* __restrict__ fc1W, const float* __restrict__ fc1b,
                           const float* __restrict__ fc2W, const float* __restrict__ fc2b,
                           const float* __restrict__ fc3W, const float* __restrict__ fc3b,
                           float* __restrict__ out) {
    int g = blockIdx.x * blockDim.x + threadIdx.x;
    if (g >= N_GRAPHS) return;
    float a[50];
#pragma unroll
    for (int k = 0; k < 50; ++k) a[k] = G[g * 50 + k];
    float h1[30];
#pragma unroll
    for (int j = 0; j < 30; ++j) {
        float acc = fc1b[j];
#pragma unroll
        for (int k = 0; k < 50; ++k) acc = fmaf(a[k], fc1W[k * 30 + j], acc);
        h1[j] = lrelu(acc);
    }
    float h2[20];
#pragma unroll
    for (int j = 0; j < 20; ++j) {
        float acc = fc2b[j];
#pragma unroll
        for (int k = 0; k < 30; ++k) acc = fmaf(h1[k], fc2W[k * 20 + j], acc);
        h2[j] = lrelu(acc);
    }
    float z0 = fc3b[0], z1 = fc3b[1];
#pragma unroll
    for (int k = 0; k < 20; ++k) {
        z0 = fmaf(h2[k], fc3W[k * 2 + 0], z0);
        z1 = fmaf(h2[k], fc3W[k * 2 + 1], z1);
    }
    float m = fmaxf(z0, z1);
    float lse = m + logf(expf(z0 - m) + expf(z1 - m));
    out[g * 2 + 0] = z0 - lse;
    out[g * 2 + 1] = z1 - lse;
}

extern "C" void kernel_launch(void* const* d_in, const int* in_sizes, int n_in,
                              void* d_out, int out_size, void* d_ws, size_t ws_size,
                              hipStream_t stream) {
    const float* x     = (const float*)d_in[0];
    const int*   ei    = (const int*)d_in[1];
    const int*   batch = (const int*)d_in[2];
    const float* W1 = (const float*)d_in[3];  const float* b1 = (const float*)d_in[4];
    const float* W2 = (const float*)d_in[5];  const float* b2 = (const float*)d_in[6];
    const float* W3 = (const float*)d_in[7];  const float* b3 = (const float*)d_in[8];
    const float* W4 = (const float*)d_in[9];  const float* b4 = (const float*)d_in[10];
    const float* bng = (const float*)d_in[11]; const float* bnb = (const float*)d_in[12];
    const float* fc1W = (const float*)d_in[13]; const float* fc1b = (const float*)d_in[14];
    const float* fc2W = (const float*)d_in[15]; const float* fc2b = (const float*)d_in[16];
    const float* fc3W = (const float*)d_in[17]; const float* fc3b = (const float*)d_in[18];

    const int* src = ei;
    const int* dst = ei + N_EDGES;

    // ---- workspace layout ----
    char* w = (char*)d_ws;
    unsigned short* bufA = (unsigned short*)w;      w += (size_t)6400000 * 2;  // 12.8 MB
    unsigned short* bufB = (unsigned short*)w;      w += (size_t)6400000 * 2;  // 12.8 MB
    int*   adj  = (int*)w;                          w += (size_t)N_EDGES * 4;  // 6.4 MB
    int*   deg  = (int*)w;                          w += (size_t)N_NODES * 4;
    int*   cursor = (int*)w;                        w += (size_t)N_NODES * 4;
    int*   base = (int*)w;                          w += (size_t)(N_NODES + 1) * 4;
    int*   chunkSum = (int*)w;                      w += 512 * 4;
    float* bnsum = (float*)w;                       w += 64 * 4;
    float* bnssum = (float*)w;                      w += 64 * 4;
    float* mu   = (float*)w;                        w += 64 * 4;
    float* rsig = (float*)w;                        w += 64 * 4;
    int*   bounds = (int*)w;                        w += (N_GRAPHS + 1) * 4;
    float* G    = (float*)w;                        w += (size_t)N_GRAPHS * 50 * 4;

    dim3 blk(256);
    const int edgeBlocks = (N_EDGES + 255) / 256;
    const int mmBlocks = (N_NODES + 63) / 64;

    // ---- CSR build (by dst) ----
    hipMemsetAsync(deg, 0, (size_t)N_NODES * 4, stream);
    hipMemsetAsync(cursor, 0, (size_t)N_NODES * 4, stream);
    degree_kernel<<<edgeBlocks, blk, 0, stream>>>(dst, deg);
    scan_chunks_kernel<<<NCHUNKS, blk, 0, stream>>>(deg, base, chunkSum);
    scan_tops_kernel<<<1, 512, 0, stream>>>(chunkSum);
    add_offsets_kernel<<<(N_NODES + 255) / 256, blk, 0, stream>>>(base, chunkSum);
    find_bounds_kernel<<<2, 256, 0, stream>>>(batch, bounds);

    // ---- FUSED: fill_adj (XCD-partitioned) ∥ matmul L1 (x@W1 -> T1) ----
    fill_and_mm1<<<FILL_BLOCKS + MM1_BLOCKS, blk, 0, stream>>>(src, dst, base, cursor, adj,
                                                               x, W1, bufA);

    // ---- L1 agg: h1 = lrelu(agg(T1) + b1) ----
    gather_agg_bf16<16, true, true><<<(N_NODES * 8 + 255) / 256, blk, 0, stream>>>(bufA, base, adj, b1, bufB);

    // ---- L2: s2 = agg(h1); h2 = lrelu(s2 @ W2 + b2) [16->32] ----
    gather_agg_bf16<16, false, false><<<(N_NODES * 8 + 255) / 256, blk, 0, stream>>>(bufB, base, adj, nullptr, bufA);
    matmul_bf16<16, 32, false, true, true><<<mmBlocks, blk, 0, stream>>>(bufA, W2, bufB, b2);

    // ---- L3: s3 = agg(h2); h3 = lrelu(s3 @ W3 + b3) [32->64] ----
    gather_agg_bf16<32, false, false><<<(N_NODES * 16 + 255) / 256, blk, 0, stream>>>(bufB, base, adj, nullptr, bufA);
    matmul_bf16<32, 64, false, true, true><<<mmBlocks, blk, 0, stream>>>(bufA, W3, bufB, b3);

    // ---- L4: T4 = h3 @ W4 [64->50]; h4 = agg(T4) + b4 ----
    matmul_bf16<64, 50, false, false, false><<<mmBlocks, blk, 0, stream>>>(bufB, W4, bufA, nullptr);
    gather_agg_bf16<50, true, false><<<(N_NODES * 25 + 255) / 256, blk, 0, stream>>>(bufA, base, adj, b4, bufB);

    // ---- BatchNorm stats ----
    hipMemsetAsync(bnsum, 0, 128 * 4, stream);
    bn_partial_kernel<<<256, blk, 0, stream>>>(bufB, bnsum, bnssum);
    bn_finalize_kernel<<<1, 64, 0, stream>>>(bnsum, bnssum, mu, rsig);

    // ---- BN apply + lrelu + segmented pool (no atomics) ----
    pool_seg_kernel<<<N_GRAPHS, blk, 0, stream>>>(bufB, bounds, mu, rsig, bng, bnb, G);

    // ---- MLP head ----
    mlp_kernel<<<1, 256, 0, stream>>>(G, fc1W, fc1b, fc2W, fc2b, fc3W, fc3b, (float*)d_out);
}